// Round 15
// baseline (3019.206 us; speedup 1.0000x reference)
//
#include <hip/hip_runtime.h>
#include <stdint.h>

#define BATCH   4096
#define KDIM    4096      // 2*2048 encode contraction
#define FDIM    16384
#define DDIM    4096
#define TOPK    64

typedef _Float16 half4v __attribute__((ext_vector_type(4)));
typedef _Float16 half8v __attribute__((ext_vector_type(8)));
typedef float    f32x4  __attribute__((ext_vector_type(4)));

// ---------------------------------------------------------------------------
// Wenc transpose: WT[f][k] = W[k][f]. 64x64 LDS tiles (round-14 validated).
// ---------------------------------------------------------------------------
__global__ __launch_bounds__(256) void transpose_wenc(
    const float* __restrict__ W,    // (KDIM, FDIM)
    float* __restrict__ WT)         // (FDIM, KDIM)
{
    __shared__ float t[64][65];
    const int nbk = KDIM / 64;
    int bk = (blockIdx.x % nbk) * 64;
    int bf = (blockIdx.x / nbk) * 64;
    int tid = threadIdx.x;
    int xx = tid & 63;
    int yy = tid >> 6;
    #pragma unroll
    for (int j = 0; j < 16; ++j) {
        int k = yy + j * 4;
        t[k][xx] = W[(size_t)(bk + k) * FDIM + bf + xx];
    }
    __syncthreads();
    #pragma unroll
    for (int j = 0; j < 16; ++j) {
        int f = yy + j * 4;
        WT[(size_t)(bf + f) * KDIM + bk + xx] = t[xx][f];
    }
}

// ---------------------------------------------------------------------------
// Wdec f32 -> bf16 (RTNE) into workspace (round-12 validated).
// ---------------------------------------------------------------------------
__device__ inline ushort f2bf(float f) {
    uint32_t u = __float_as_uint(f);
    return (ushort)((u + 0x7fffu + ((u >> 16) & 1u)) >> 16);
}

__global__ __launch_bounds__(256) void wdec_to_bf16(
    const float* __restrict__ Wdec, ushort* __restrict__ Wb)
{
    const size_t total4 = (size_t)FDIM * DDIM / 4;
    size_t stride = (size_t)gridDim.x * blockDim.x;
    for (size_t i = (size_t)blockIdx.x * blockDim.x + threadIdx.x; i < total4; i += stride) {
        float4 v = *(const float4*)(Wdec + i * 4);
        ushort4 o;
        o.x = f2bf(v.x); o.y = f2bf(v.y); o.z = f2bf(v.z); o.w = f2bf(v.w);
        *(ushort4*)(Wb + i * 4) = o;
    }
}

// ---------------------------------------------------------------------------
// Encode 1-product, BK=64, B sourced from WencT (k-contiguous rows).
// pre is bit-identical to round-14's encode_mfma_1p: same RTNE casts, same
// K-accumulation order, same lane->k mapping on A and B (permutation cancels).
// Swizzle: chunk g ^= (row&7) for 128B rows; <=2-way on all b128 accesses.
// ---------------------------------------------------------------------------
__global__ __launch_bounds__(256) void encode_mfma_1p_bt(
    const float* __restrict__ A,      // (BATCH, KDIM)
    const float* __restrict__ BT,     // (FDIM, KDIM)  = WencT
    const float* __restrict__ bias,
    float* __restrict__ C)
{
    __shared__ _Float16 Ah[128 * 64];   // 16KB, [m][k] chunks swizzled
    __shared__ _Float16 Bh[128 * 64];   // 16KB, 8 subtiles [16col][64k] swizzled

    int nwg = gridDim.x;
    int cpx = nwg >> 3;
    int bid = blockIdx.x;
    int wg  = (bid & 7) * cpx + (bid >> 3);

    int bm = (wg & 31) << 7;            // bn-major
    int bn = (wg >> 5) << 7;

    int tid  = threadIdx.x;
    int wave = tid >> 6, lane = tid & 63;
    int wr = wave >> 1, wc = wave & 1;
    int lrow = lane & 15, lgrp = lane >> 4;

    int colw = tid & 127;               // B staging: column (= WencT row)
    int kh   = tid >> 7;                // k-half of the 64-wide tile
    int nbw  = colw >> 4;
    int colb = colw & 15;

    const float* Arow = A + (size_t)bm * KDIM;
    const float* Brow = BT + (size_t)(bn + colw) * KDIM + kh * 32;

    // prologue: tile 0
    float4 areg[8], breg[8];
    #pragma unroll
    for (int i = 0; i < 8; ++i) {
        int idx = tid + i * 256;
        areg[i] = *(const float4*)(Arow + (size_t)(idx >> 4) * KDIM + ((idx & 15) << 2));
    }
    #pragma unroll
    for (int j = 0; j < 8; ++j)
        breg[j] = *(const float4*)(Brow + j * 4);

    f32x4 zero = {0.0f, 0.0f, 0.0f, 0.0f};
    f32x4 acc[4][4];
    #pragma unroll
    for (int mf = 0; mf < 4; ++mf)
        #pragma unroll
        for (int nf = 0; nf < 4; ++nf) acc[mf][nf] = zero;

    for (int kt = 0; kt < KDIM; kt += 64) {
        __syncthreads();

        // ---- stage A: f32 -> f16, swizzled chunks ----
        #pragma unroll
        for (int i = 0; i < 8; ++i) {
            int idx = tid + i * 256;
            int m   = idx >> 4;
            int q   = idx & 15;          // float4 slot in 64-f32 row
            int g   = q >> 1;            // 16B chunk (8 f16)
            int hf  = (q & 1) << 2;      // half-chunk offset (f16 units)
            int off = m * 64 + ((g ^ (m & 7)) << 3) + hf;
            half4v h;
            h[0] = (_Float16)areg[i].x; h[1] = (_Float16)areg[i].y;
            h[2] = (_Float16)areg[i].z; h[3] = (_Float16)areg[i].w;
            *(half4v*)&Ah[off] = h;
        }
        // ---- stage B: f32 -> f16, 4 chunks, swizzled by column ----
        #pragma unroll
        for (int c2 = 0; c2 < 4; ++c2) {
            half8v g8;
            float4 v0 = breg[c2 * 2], v1 = breg[c2 * 2 + 1];
            g8[0] = (_Float16)v0.x; g8[1] = (_Float16)v0.y;
            g8[2] = (_Float16)v0.z; g8[3] = (_Float16)v0.w;
            g8[4] = (_Float16)v1.x; g8[5] = (_Float16)v1.y;
            g8[6] = (_Float16)v1.z; g8[7] = (_Float16)v1.w;
            int c  = kh * 4 + c2;
            int cp = c ^ (colb & 7);
            int off = nbw * 1024 + colb * 64 + cp * 8;
            *(half8v*)&Bh[off] = g8;
        }
        __syncthreads();

        // ---- issue next tile's global loads (complete under MFMA) ----
        if (kt + 64 < KDIM) {
            #pragma unroll
            for (int i = 0; i < 8; ++i) {
                int idx = tid + i * 256;
                areg[i] = *(const float4*)(Arow + (size_t)(idx >> 4) * KDIM + kt + 64 + ((idx & 15) << 2));
            }
            #pragma unroll
            for (int j = 0; j < 8; ++j)
                breg[j] = *(const float4*)(Brow + kt + 64 + j * 4);
        }

        // ---- fragments + MFMA: two K-steps of 32 ----
        #pragma unroll
        for (int kk = 0; kk < 2; ++kk) {
            half8v ahf[4], bhf[4];
            #pragma unroll
            for (int mf = 0; mf < 4; ++mf) {
                int m   = wr * 64 + mf * 16 + lrow;
                int g   = kk * 4 + lgrp;
                int off = m * 64 + ((g ^ (m & 7)) << 3);
                ahf[mf] = *(half8v*)&Ah[off];
            }
            #pragma unroll
            for (int nf = 0; nf < 4; ++nf) {
                int nb  = wc * 4 + nf;
                int cp  = (kk * 4 + lgrp) ^ (lrow & 7);
                int off = nb * 1024 + lrow * 64 + cp * 8;
                bhf[nf] = *(half8v*)&Bh[off];
            }
            #pragma unroll
            for (int mf = 0; mf < 4; ++mf)
                #pragma unroll
                for (int nf = 0; nf < 4; ++nf)
                    acc[mf][nf] = __builtin_amdgcn_mfma_f32_16x16x32_f16(ahf[mf], bhf[nf], acc[mf][nf], 0, 0, 0);
        }
    }

    #pragma unroll
    for (int nf = 0; nf < 4; ++nf) {
        int col = bn + wc * 64 + nf * 16 + lrow;
        float bb = bias[col];
        #pragma unroll
        for (int mf = 0; mf < 4; ++mf) {
            int row0 = bm + wr * 64 + mf * 16 + lgrp * 4;
            #pragma unroll
            for (int r = 0; r < 4; ++r) {
                float v = acc[mf][nf][r] + bb;
                C[(size_t)(row0 + r) * FDIM + col] = (v > 0.0f) ? v : 0.0f;
            }
        }
    }
}

// ---------------------------------------------------------------------------
// Encode 2-product (round-10..12 validated verbatim) — fallback path.
// ---------------------------------------------------------------------------
__global__ __launch_bounds__(256) void encode_mfma(
    const float* __restrict__ A,
    const float* __restrict__ B,
    const float* __restrict__ bias,
    float* __restrict__ C)
{
    __shared__ _Float16 Ah[128 * 32];
    __shared__ _Float16 Al[128 * 32];
    __shared__ _Float16 Bh[128 * 32];

    int nwg = gridDim.x;
    int cpx = nwg >> 3;
    int bid = blockIdx.x;
    int wg  = (bid & 7) * cpx + (bid >> 3);

    int bm = (wg & 31) << 7;
    int bn = (wg >> 5) << 7;

    int tid  = threadIdx.x;
    int wave = tid >> 6, lane = tid & 63;
    int wr = wave >> 1, wc = wave & 1;
    int lrow = lane & 15, lgrp = lane >> 4;

    int colw = tid & 127;
    int kh   = tid >> 7;
    int nbw  = colw >> 4;
    int colb = colw & 15;

    const float* Arow = A + (size_t)bm * KDIM;

    float4 areg[4];
    float  breg[16];
    #pragma unroll
    for (int i = 0; i < 4; ++i) {
        int idx = tid + i * 256;
        areg[i] = *(const float4*)(Arow + (size_t)(idx >> 3) * KDIM + ((idx & 7) << 2));
    }
    #pragma unroll
    for (int kk = 0; kk < 16; ++kk)
        breg[kk] = B[(size_t)(kh * 16 + kk) * FDIM + bn + colw];

    f32x4 zero = {0.0f, 0.0f, 0.0f, 0.0f};
    f32x4 acc[4][4];
    #pragma unroll
    for (int mf = 0; mf < 4; ++mf)
        #pragma unroll
        for (int nf = 0; nf < 4; ++nf) acc[mf][nf] = zero;

    for (int kt = 0; kt < KDIM; kt += 32) {
        __syncthreads();

        #pragma unroll
        for (int i = 0; i < 4; ++i) {
            int idx = tid + i * 256;
            int m   = idx >> 3;
            int g   = (idx & 7) >> 1;
            int hf  = (idx & 1) << 2;
            int off = m * 32 + ((g ^ ((m >> 1) & 3)) << 3) + hf;
            float v[4] = {areg[i].x, areg[i].y, areg[i].z, areg[i].w};
            half4v h1, h2;
            #pragma unroll
            for (int j = 0; j < 4; ++j) {
                _Float16 h = (_Float16)v[j];
                h1[j] = h;
                h2[j] = (_Float16)(v[j] - (float)h);
            }
            *(half4v*)&Ah[off] = h1;
            *(half4v*)&Al[off] = h2;
        }
        {
            half8v g0h, g1h;
            #pragma unroll
            for (int kk = 0; kk < 8; ++kk) {
                g0h[kk] = (_Float16)breg[kk];
                g1h[kk] = (_Float16)breg[8 + kk];
            }
            int g0 = kh * 2, g1 = kh * 2 + 1;
            int off0 = nbw * 512 + ((colb * 4 + (g0 ^ ((colb >> 1) & 3))) << 3);
            int off1 = nbw * 512 + ((colb * 4 + (g1 ^ ((colb >> 1) & 3))) << 3);
            *(half8v*)&Bh[off0] = g0h;
            *(half8v*)&Bh[off1] = g1h;
        }
        __syncthreads();

        if (kt + 32 < KDIM) {
            #pragma unroll
            for (int i = 0; i < 4; ++i) {
                int idx = tid + i * 256;
                areg[i] = *(const float4*)(Arow + (size_t)(idx >> 3) * KDIM + kt + 32 + ((idx & 7) << 2));
            }
            #pragma unroll
            for (int kk = 0; kk < 16; ++kk)
                breg[kk] = B[(size_t)(kt + 32 + kh * 16 + kk) * FDIM + bn + colw];
        }

        half8v ahf[4], alf[4], bhf[4];
        #pragma unroll
        for (int mf = 0; mf < 4; ++mf) {
            int m   = wr * 64 + mf * 16 + lrow;
            int off = m * 32 + ((lgrp ^ ((m >> 1) & 3)) << 3);
            ahf[mf] = *(half8v*)&Ah[off];
            alf[mf] = *(half8v*)&Al[off];
        }
        #pragma unroll
        for (int nf = 0; nf < 4; ++nf) {
            int nb  = wc * 4 + nf;
            int off = nb * 512 + ((lrow * 4 + (lgrp ^ ((lrow >> 1) & 3))) << 3);
            bhf[nf] = *(half8v*)&Bh[off];
        }

        #pragma unroll
        for (int mf = 0; mf < 4; ++mf)
            #pragma unroll
            for (int nf = 0; nf < 4; ++nf) {
                acc[mf][nf] = __builtin_amdgcn_mfma_f32_16x16x32_f16(ahf[mf], bhf[nf], acc[mf][nf], 0, 0, 0);
                acc[mf][nf] = __builtin_amdgcn_mfma_f32_16x16x32_f16(alf[mf], bhf[nf], acc[mf][nf], 0, 0, 0);
            }
    }

    #pragma unroll
    for (int nf = 0; nf < 4; ++nf) {
        int col = bn + wc * 64 + nf * 16 + lrow;
        float bb = bias[col];
        #pragma unroll
        for (int mf = 0; mf < 4; ++mf) {
            int row0 = bm + wr * 64 + mf * 16 + lgrp * 4;
            #pragma unroll
            for (int r = 0; r < 4; ++r) {
                float v = acc[mf][nf][r] + bb;
                C[(size_t)(row0 + r) * FDIM + col] = (v > 0.0f) ? v : 0.0f;
            }
        }
    }
}

// ---------------------------------------------------------------------------
// Fused top-k + decode — round-14 validated verbatim.
// ---------------------------------------------------------------------------
#define MAXCAND  32
#define LISTCAP  96

__global__ __launch_bounds__(512) void topk_decode(
    float* __restrict__ feat,
    const float* __restrict__ x,
    const float* __restrict__ Wenc,
    const float* __restrict__ WencT,
    const float* __restrict__ benc,
    const float* __restrict__ Wdec,
    const ushort* __restrict__ Wb,
    const float* __restrict__ bdec,
    const float* __restrict__ dmask,
    float* __restrict__ recon,
    float eps)
{
    int b   = blockIdx.x;
    int tid = threadIdx.x;
    int wv  = tid >> 6;
    int lane = tid & 63;
    float* frow = feat + (size_t)b * FDIM;

    float r[32];
    #pragma unroll
    for (int i = 0; i < 32; ++i) r[i] = frow[tid + i * 512];

    __shared__ uint32_t hist[8][256];
    __shared__ uint32_t scan[256];
    __shared__ uint32_t sh_prefix, sh_rem;
    __shared__ int   s_ncand, s_ndef, s_n;
    __shared__ int   s_cidx[MAXCAND];
    __shared__ float s_cval[MAXCAND];
    __shared__ int   s_sel[MAXCAND];
    __shared__ int   L_idx[LISTCAP];
    __shared__ float L_v0[LISTCAP], L_v1[LISTCAP];
    __shared__ double s_exact[MAXCAND];

    if (tid == 0) { s_ncand = 0; s_ndef = 0; s_n = 0; }

    #pragma unroll
    for (int i = 0; i < 4; ++i) ((uint32_t*)hist)[tid + i * 512] = 0u;
    __syncthreads();
    #pragma unroll
    for (int i = 0; i < 32; ++i) {
        uint32_t u = __float_as_uint(r[i]);
        if (u) atomicAdd(&hist[wv][u >> 24], 1u);
    }
    __syncthreads();
    if (tid < 256) {
        int rb = 255 - tid;
        uint32_t s = 0;
        #pragma unroll
        for (int w = 0; w < 8; ++w) s += hist[w][rb];
        scan[tid] = s;
    }
    __syncthreads();
    #pragma unroll
    for (int ofs = 1; ofs < 256; ofs <<= 1) {
        uint32_t tv = 0;
        if (tid < 256 && tid >= ofs) tv = scan[tid - ofs];
        __syncthreads();
        if (tid < 256) scan[tid] += tv;
        __syncthreads();
    }
    bool small = (scan[255] <= TOPK);

    uint32_t prefix = 0, rem = TOPK;
    if (!small) {
        if (tid < 256) {
            uint32_t cum  = scan[tid];
            uint32_t prev = (tid == 0) ? 0u : scan[tid - 1];
            if (cum >= rem && prev < rem) {
                sh_prefix = (uint32_t)(255 - tid);
                sh_rem    = rem - prev;
            }
        }
        __syncthreads();
        prefix = sh_prefix;
        rem    = sh_rem;
        __syncthreads();

        for (int byt = 2; byt >= 0; --byt) {
            #pragma unroll
            for (int i = 0; i < 4; ++i) ((uint32_t*)hist)[tid + i * 512] = 0u;
            __syncthreads();
            int shift_hi = (byt + 1) * 8;
            #pragma unroll
            for (int i = 0; i < 32; ++i) {
                uint32_t u = __float_as_uint(r[i]);
                if ((u >> shift_hi) == prefix)
                    atomicAdd(&hist[wv][(u >> (byt * 8)) & 255u], 1u);
            }
            __syncthreads();
            if (tid < 256) {
                int rb = 255 - tid;
                uint32_t s = 0;
                #pragma unroll
                for (int w = 0; w < 8; ++w) s += hist[w][rb];
                scan[tid] = s;
            }
            __syncthreads();
            #pragma unroll
            for (int ofs = 1; ofs < 256; ofs <<= 1) {
                uint32_t tv = 0;
                if (tid < 256 && tid >= ofs) tv = scan[tid - ofs];
                __syncthreads();
                if (tid < 256) scan[tid] += tv;
                __syncthreads();
            }
            if (tid < 256) {
                uint32_t cum  = scan[tid];
                uint32_t prev = (tid == 0) ? 0u : scan[tid - 1];
                if (cum >= rem && prev < rem) {
                    sh_prefix = (prefix << 8) | (uint32_t)(255 - tid);
                    sh_rem    = rem - prev;
                }
            }
            __syncthreads();
            prefix = sh_prefix;
            rem    = sh_rem;
            __syncthreads();
        }

        float T  = __uint_as_float(prefix);
        float hi = T + eps;
        float lo = T - eps;

        int mydef = 0;
        #pragma unroll
        for (int i = 0; i < 32; ++i) {
            float val = r[i];
            int   f   = tid + i * 512;
            if (val > hi) {
                ++mydef;
                int s = atomicAdd(&s_n, 1);
                if (s < LISTCAP) {
                    L_idx[s] = f;
                    L_v0[s]  = val * dmask[2 * f + 0];
                    L_v1[s]  = val * dmask[2 * f + 1];
                }
            } else if (val >= lo && val > 0.0f) {
                int s = atomicAdd(&s_ncand, 1);
                if (s < MAXCAND) { s_cidx[s] = f; s_cval[s] = val; }
                r[i] = 0.0f;
            } else {
                r[i] = 0.0f;
            }
        }
        atomicAdd(&s_ndef, mydef);
        #pragma unroll
        for (int i = 0; i < 32; ++i) frow[tid + i * 512] = r[i];
        __syncthreads();

        int A    = (s_ncand < MAXCAND) ? s_ncand : MAXCAND;
        int need = TOPK - s_ndef;

        if (A > need) {
            const float* xr = x + (size_t)b * KDIM;
            if (WencT != nullptr) {
                const float4* x4 = (const float4*)xr;
                for (int c0 = 0; c0 < A; c0 += 8) {
                    int c = c0 + wv;
                    if (c < A) {
                        int f = s_cidx[c];
                        const float4* wt = (const float4*)(WencT + (size_t)f * KDIM);
                        double s = 0.0;
                        #pragma unroll
                        for (int i = 0; i < 16; ++i) {
                            float4 wv4 = wt[lane + i * 64];
                            float4 xv4 = x4[lane + i * 64];
                            s += (double)xv4.x * (double)wv4.x + (double)xv4.y * (double)wv4.y
                               + (double)xv4.z * (double)wv4.z + (double)xv4.w * (double)wv4.w;
                        }
                        #pragma unroll
                        for (int ofs = 32; ofs > 0; ofs >>= 1)
                            s += __shfl_down(s, ofs, 64);
                        if (lane == 0) s_exact[c] = s + (double)benc[f];
                    }
                }
            } else {
                for (int c0 = 0; c0 < A; c0 += 8) {
                    int c = c0 + wv;
                    if (c < A) {
                        int f = s_cidx[c];
                        double s = 0.0;
                        #pragma unroll 8
                        for (int i = 0; i < 64; ++i) {
                            int k = lane + i * 64;
                            s += (double)xr[k] * (double)Wenc[(size_t)k * FDIM + f];
                        }
                        #pragma unroll
                        for (int ofs = 32; ofs > 0; ofs >>= 1)
                            s += __shfl_down(s, ofs, 64);
                        if (lane == 0) s_exact[c] = s + (double)benc[f];
                    }
                }
            }
            __syncthreads();
            if (tid == 0) {
                for (int c = 0; c < A; ++c) s_sel[c] = 0;
                for (int rr = 0; rr < need; ++rr) {
                    int best = -1;
                    for (int c = 0; c < A; ++c) {
                        if (s_sel[c]) continue;
                        if (best < 0 || s_exact[c] > s_exact[best] ||
                            (s_exact[c] == s_exact[best] && s_cidx[c] < s_cidx[best]))
                            best = c;
                    }
                    if (best >= 0) s_sel[best] = 1;
                }
            }
        } else {
            if (tid == 0)
                for (int c = 0; c < A; ++c) s_sel[c] = 1;
        }
        __syncthreads();

        if (tid < A && s_sel[tid]) {
            int   f   = s_cidx[tid];
            float val = s_cval[tid];
            frow[f] = val;
            int s = atomicAdd(&s_n, 1);
            if (s < LISTCAP) {
                L_idx[s] = f;
                L_v0[s]  = val * dmask[2 * f + 0];
                L_v1[s]  = val * dmask[2 * f + 1];
            }
        }
        __syncthreads();
    } else {
        #pragma unroll
        for (int i = 0; i < 32; ++i) {
            float val = r[i];
            if (val != 0.0f) {
                int f = tid + i * 512;
                int s = atomicAdd(&s_n, 1);
                if (s < LISTCAP) {
                    L_idx[s] = f;
                    L_v0[s]  = val * dmask[2 * f + 0];
                    L_v1[s]  = val * dmask[2 * f + 1];
                }
            }
        }
        __syncthreads();
    }

    int n = (s_n < LISTCAP) ? s_n : LISTCAP;

    const float4* b4 = (const float4*)bdec;
    float4 a0 = b4[tid];
    float4 a1 = b4[tid + 512];

    if (Wb != nullptr) {
        #pragma unroll 4
        for (int t = 0; t < n; ++t) {
            int f = L_idx[t];
            float s0 = L_v0[t], s1 = L_v1[t];
            const ushort4* w = (const ushort4*)(Wb + (size_t)f * DDIM);
            ushort4 u0 = w[tid];
            ushort4 u1 = w[tid + 512];
            a0.x = fmaf(s0, __uint_as_float((uint32_t)u0.x << 16), a0.x);
            a0.y = fmaf(s0, __uint_as_float((uint32_t)u0.y << 16), a0.y);
            a0.z = fmaf(s0, __uint_as_float((uint32_t)u0.z << 16), a0.z);
            a0.w = fmaf(s0, __uint_as_float((uint32_t)u0.w << 16), a0.w);
            a1.x = fmaf(s1, __uint_as_float((uint32_t)u1.x << 16), a1.x);
            a1.y = fmaf(s1, __uint_as_float((uint32_t)u1.y << 16), a1.y);
            a1.z = fmaf(s1, __uint_as_float((uint32_t)u1.z << 16), a1.z);
            a1.w = fmaf(s1, __uint_as_float((uint32_t)u1.w << 16), a1.w);
        }
    } else {
        #pragma unroll 4
        for (int t = 0; t < n; ++t) {
            int f = L_idx[t];
            float s0 = L_v0[t], s1 = L_v1[t];
            const float4* w = (const float4*)(Wdec + (size_t)f * DDIM);
            float4 w0 = w[tid];
            float4 w1 = w[tid + 512];
            a0.x = fmaf(s0, w0.x, a0.x); a0.y = fmaf(s0, w0.y, a0.y);
            a0.z = fmaf(s0, w0.z, a0.z); a0.w = fmaf(s0, w0.w, a0.w);
            a1.x = fmaf(s1, w1.x, a1.x); a1.y = fmaf(s1, w1.y, a1.y);
            a1.z = fmaf(s1, w1.z, a1.z); a1.w = fmaf(s1, w1.w, a1.w);
        }
    }

    float4* out = (float4*)(recon + (size_t)b * DDIM);
    out[tid]       = a0;
    out[tid + 512] = a1;
}

// ---------------------------------------------------------------------------
extern "C" void kernel_launch(void* const* d_in, const int* in_sizes, int n_in,
                              void* d_out, int out_size, void* d_ws, size_t ws_size,
                              hipStream_t stream)
{
    const float* x     = (const float*)d_in[0];
    const float* Wenc  = (const float*)d_in[1];
    const float* benc  = (const float*)d_in[2];
    const float* Wdec  = (const float*)d_in[3];
    const float* bdec  = (const float*)d_in[4];
    const float* dmask = (const float*)d_in[5];

    float* recon = (float*)d_out;
    float* feat  = recon + (size_t)BATCH * DDIM;

    const size_t MB = 1024 * 1024;
    // ws layout (full): [WencT f32 256MB][Wdec-bf16 128MB]
    bool wt    = (ws_size >= 256 * MB);
    bool wball = (ws_size >= 384 * MB);

    char* wsb = (char*)d_ws;
    float* WencT = wt ? (float*)wsb : nullptr;
    ushort* Wb = nullptr;
    if (wball)                         Wb = (ushort*)(wsb + 256 * MB);
    else if (!wt && ws_size >= 128*MB) Wb = (ushort*)wsb;   // round-12 behavior

    if (wt)
        transpose_wenc<<<dim3((KDIM / 64) * (FDIM / 64)), 256, 0, stream>>>(Wenc, WencT);
    if (Wb)
        wdec_to_bf16<<<dim3(2048), 256, 0, stream>>>(Wdec, Wb);

    float eps;
    if (wt) {
        eps = 1e-2f;   // 1-product encode error <= ~3.4e-3; cheap refinement
        encode_mfma_1p_bt<<<dim3((BATCH / 128) * (FDIM / 128)), 256, 0, stream>>>(x, WencT, benc, feat);
    } else {
        eps = 5e-3f;   // 2-product encode (round-12 exact config)
        encode_mfma<<<dim3((BATCH / 128) * (FDIM / 128)), 256, 0, stream>>>(x, Wenc, benc, feat);
    }

    topk_decode<<<dim3(BATCH), 512, 0, stream>>>(feat, x, Wenc, WencT, benc,
                                                 Wdec, Wb, bdec, dmask, recon, eps);
}

// Round 16
// 1929.075 us; speedup vs baseline: 1.5651x; 1.5651x over previous
//
#include <hip/hip_runtime.h>
#include <stdint.h>

#define BATCH   4096
#define KDIM    4096      // 2*2048 encode contraction
#define FDIM    16384
#define DDIM    4096
#define TOPK    64

typedef _Float16 half4v __attribute__((ext_vector_type(4)));
typedef _Float16 half8v __attribute__((ext_vector_type(8)));
typedef float    f32x4  __attribute__((ext_vector_type(4)));

// ---------------------------------------------------------------------------
// Wenc transpose: WT[f][k] = W[k][f]. 64x64 LDS tiles (round-14 validated).
// ---------------------------------------------------------------------------
__global__ __launch_bounds__(256) void transpose_wenc(
    const float* __restrict__ W,    // (KDIM, FDIM)
    float* __restrict__ WT)         // (FDIM, KDIM)
{
    __shared__ float t[64][65];
    const int nbk = KDIM / 64;
    int bk = (blockIdx.x % nbk) * 64;
    int bf = (blockIdx.x / nbk) * 64;
    int tid = threadIdx.x;
    int xx = tid & 63;
    int yy = tid >> 6;
    #pragma unroll
    for (int j = 0; j < 16; ++j) {
        int k = yy + j * 4;
        t[k][xx] = W[(size_t)(bk + k) * FDIM + bf + xx];
    }
    __syncthreads();
    #pragma unroll
    for (int j = 0; j < 16; ++j) {
        int f = yy + j * 4;
        WT[(size_t)(bf + f) * KDIM + bk + xx] = t[xx][f];
    }
}

// ---------------------------------------------------------------------------
// Wdec f32 -> bf16 (RTNE) into workspace (round-12 validated).
// ---------------------------------------------------------------------------
__device__ inline ushort f2bf(float f) {
    uint32_t u = __float_as_uint(f);
    return (ushort)((u + 0x7fffu + ((u >> 16) & 1u)) >> 16);
}

__global__ __launch_bounds__(256) void wdec_to_bf16(
    const float* __restrict__ Wdec, ushort* __restrict__ Wb)
{
    const size_t total4 = (size_t)FDIM * DDIM / 4;
    size_t stride = (size_t)gridDim.x * blockDim.x;
    for (size_t i = (size_t)blockIdx.x * blockDim.x + threadIdx.x; i < total4; i += stride) {
        float4 v = *(const float4*)(Wdec + i * 4);
        ushort4 o;
        o.x = f2bf(v.x); o.y = f2bf(v.y); o.z = f2bf(v.z); o.w = f2bf(v.w);
        *(ushort4*)(Wb + i * 4) = o;
    }
}

// ---------------------------------------------------------------------------
// Encode 1-product (round-14 validated body). ONLY change: 2D-chunked block
// ordering within each XCD — 4 bn panels per chunk, bn-fastest — so the A
// matrix streams once per CHUNK (4 sweeps/XCD) instead of once per bn panel
// (16 sweeps/XCD). Pure index remap; output bit-identical.
// ---------------------------------------------------------------------------
__global__ __launch_bounds__(256) void encode_mfma_1p(
    const float* __restrict__ A,
    const float* __restrict__ B,
    const float* __restrict__ bias,
    float* __restrict__ C)
{
    __shared__ _Float16 Ah[128 * 32];   // [m][k], chunk-swizzled rows of 64B
    __shared__ _Float16 Bh[128 * 32];   // 8 subtiles [16col][32k], swizzled

    int nwg = gridDim.x;                // 4096
    int cpx = nwg >> 3;                 // 512
    int bid = blockIdx.x;
    int wg  = (bid & 7) * cpx + (bid >> 3);

    // chunked 2D order: XCD owns 16 bn panels; 4 chunks of 4 bn, bn fastest
    int xcd   = wg / cpx;               // 0..7
    int local = wg - xcd * cpx;         // 0..511
    int chunk = local >> 7;             // 0..3
    int inner = local & 127;            // 0..127
    int bm = (inner >> 2) << 7;                                   // 32 panels
    int bn = ((xcd << 4) + (chunk << 2) + (inner & 3)) << 7;      // 128 panels

    int tid  = threadIdx.x;
    int wave = tid >> 6, lane = tid & 63;
    int wr = wave >> 1, wc = wave & 1;
    int lrow = lane & 15, lgrp = lane >> 4;

    int colw = tid & 127;
    int kh   = tid >> 7;
    int nbw  = colw >> 4;
    int colb = colw & 15;

    const float* Arow = A + (size_t)bm * KDIM;

    float4 areg[4];
    float  breg[16];
    #pragma unroll
    for (int i = 0; i < 4; ++i) {
        int idx = tid + i * 256;
        areg[i] = *(const float4*)(Arow + (size_t)(idx >> 3) * KDIM + ((idx & 7) << 2));
    }
    #pragma unroll
    for (int kk = 0; kk < 16; ++kk)
        breg[kk] = B[(size_t)(kh * 16 + kk) * FDIM + bn + colw];

    f32x4 zero = {0.0f, 0.0f, 0.0f, 0.0f};
    f32x4 acc[4][4];
    #pragma unroll
    for (int mf = 0; mf < 4; ++mf)
        #pragma unroll
        for (int nf = 0; nf < 4; ++nf) acc[mf][nf] = zero;

    for (int kt = 0; kt < KDIM; kt += 32) {
        __syncthreads();

        #pragma unroll
        for (int i = 0; i < 4; ++i) {
            int idx = tid + i * 256;
            int m   = idx >> 3;
            int g   = (idx & 7) >> 1;
            int hf  = (idx & 1) << 2;
            int off = m * 32 + ((g ^ ((m >> 1) & 3)) << 3) + hf;
            float v[4] = {areg[i].x, areg[i].y, areg[i].z, areg[i].w};
            half4v h1;
            #pragma unroll
            for (int j = 0; j < 4; ++j) h1[j] = (_Float16)v[j];
            *(half4v*)&Ah[off] = h1;
        }
        {
            half8v g0h, g1h;
            #pragma unroll
            for (int kk = 0; kk < 8; ++kk) {
                g0h[kk] = (_Float16)breg[kk];
                g1h[kk] = (_Float16)breg[8 + kk];
            }
            int g0 = kh * 2, g1 = kh * 2 + 1;
            int off0 = nbw * 512 + ((colb * 4 + (g0 ^ ((colb >> 1) & 3))) << 3);
            int off1 = nbw * 512 + ((colb * 4 + (g1 ^ ((colb >> 1) & 3))) << 3);
            *(half8v*)&Bh[off0] = g0h;
            *(half8v*)&Bh[off1] = g1h;
        }
        __syncthreads();

        if (kt + 32 < KDIM) {
            #pragma unroll
            for (int i = 0; i < 4; ++i) {
                int idx = tid + i * 256;
                areg[i] = *(const float4*)(Arow + (size_t)(idx >> 3) * KDIM + kt + 32 + ((idx & 7) << 2));
            }
            #pragma unroll
            for (int kk = 0; kk < 16; ++kk)
                breg[kk] = B[(size_t)(kt + 32 + kh * 16 + kk) * FDIM + bn + colw];
        }

        half8v ahf[4], bhf[4];
        #pragma unroll
        for (int mf = 0; mf < 4; ++mf) {
            int m   = wr * 64 + mf * 16 + lrow;
            int off = m * 32 + ((lgrp ^ ((m >> 1) & 3)) << 3);
            ahf[mf] = *(half8v*)&Ah[off];
        }
        #pragma unroll
        for (int nf = 0; nf < 4; ++nf) {
            int nb  = wc * 4 + nf;
            int off = nb * 512 + ((lrow * 4 + (lgrp ^ ((lrow >> 1) & 3))) << 3);
            bhf[nf] = *(half8v*)&Bh[off];
        }

        #pragma unroll
        for (int mf = 0; mf < 4; ++mf)
            #pragma unroll
            for (int nf = 0; nf < 4; ++nf)
                acc[mf][nf] = __builtin_amdgcn_mfma_f32_16x16x32_f16(ahf[mf], bhf[nf], acc[mf][nf], 0, 0, 0);
    }

    #pragma unroll
    for (int nf = 0; nf < 4; ++nf) {
        int col = bn + wc * 64 + nf * 16 + lrow;
        float bb = bias[col];
        #pragma unroll
        for (int mf = 0; mf < 4; ++mf) {
            int row0 = bm + wr * 64 + mf * 16 + lgrp * 4;
            #pragma unroll
            for (int r = 0; r < 4; ++r) {
                float v = acc[mf][nf][r] + bb;
                C[(size_t)(row0 + r) * FDIM + col] = (v > 0.0f) ? v : 0.0f;
            }
        }
    }
}

// ---------------------------------------------------------------------------
// Encode 2-product (round-10..12 validated verbatim) — fallback path.
// ---------------------------------------------------------------------------
__global__ __launch_bounds__(256) void encode_mfma(
    const float* __restrict__ A,
    const float* __restrict__ B,
    const float* __restrict__ bias,
    float* __restrict__ C)
{
    __shared__ _Float16 Ah[128 * 32];
    __shared__ _Float16 Al[128 * 32];
    __shared__ _Float16 Bh[128 * 32];

    int nwg = gridDim.x;
    int cpx = nwg >> 3;
    int bid = blockIdx.x;
    int wg  = (bid & 7) * cpx + (bid >> 3);

    int bm = (wg & 31) << 7;
    int bn = (wg >> 5) << 7;

    int tid  = threadIdx.x;
    int wave = tid >> 6, lane = tid & 63;
    int wr = wave >> 1, wc = wave & 1;
    int lrow = lane & 15, lgrp = lane >> 4;

    int colw = tid & 127;
    int kh   = tid >> 7;
    int nbw  = colw >> 4;
    int colb = colw & 15;

    const float* Arow = A + (size_t)bm * KDIM;

    float4 areg[4];
    float  breg[16];
    #pragma unroll
    for (int i = 0; i < 4; ++i) {
        int idx = tid + i * 256;
        areg[i] = *(const float4*)(Arow + (size_t)(idx >> 3) * KDIM + ((idx & 7) << 2));
    }
    #pragma unroll
    for (int kk = 0; kk < 16; ++kk)
        breg[kk] = B[(size_t)(kh * 16 + kk) * FDIM + bn + colw];

    f32x4 zero = {0.0f, 0.0f, 0.0f, 0.0f};
    f32x4 acc[4][4];
    #pragma unroll
    for (int mf = 0; mf < 4; ++mf)
        #pragma unroll
        for (int nf = 0; nf < 4; ++nf) acc[mf][nf] = zero;

    for (int kt = 0; kt < KDIM; kt += 32) {
        __syncthreads();

        #pragma unroll
        for (int i = 0; i < 4; ++i) {
            int idx = tid + i * 256;
            int m   = idx >> 3;
            int g   = (idx & 7) >> 1;
            int hf  = (idx & 1) << 2;
            int off = m * 32 + ((g ^ ((m >> 1) & 3)) << 3) + hf;
            float v[4] = {areg[i].x, areg[i].y, areg[i].z, areg[i].w};
            half4v h1, h2;
            #pragma unroll
            for (int j = 0; j < 4; ++j) {
                _Float16 h = (_Float16)v[j];
                h1[j] = h;
                h2[j] = (_Float16)(v[j] - (float)h);
            }
            *(half4v*)&Ah[off] = h1;
            *(half4v*)&Al[off] = h2;
        }
        {
            half8v g0h, g1h;
            #pragma unroll
            for (int kk = 0; kk < 8; ++kk) {
                g0h[kk] = (_Float16)breg[kk];
                g1h[kk] = (_Float16)breg[8 + kk];
            }
            int g0 = kh * 2, g1 = kh * 2 + 1;
            int off0 = nbw * 512 + ((colb * 4 + (g0 ^ ((colb >> 1) & 3))) << 3);
            int off1 = nbw * 512 + ((colb * 4 + (g1 ^ ((colb >> 1) & 3))) << 3);
            *(half8v*)&Bh[off0] = g0h;
            *(half8v*)&Bh[off1] = g1h;
        }
        __syncthreads();

        if (kt + 32 < KDIM) {
            #pragma unroll
            for (int i = 0; i < 4; ++i) {
                int idx = tid + i * 256;
                areg[i] = *(const float4*)(Arow + (size_t)(idx >> 3) * KDIM + kt + 32 + ((idx & 7) << 2));
            }
            #pragma unroll
            for (int kk = 0; kk < 16; ++kk)
                breg[kk] = B[(size_t)(kt + 32 + kh * 16 + kk) * FDIM + bn + colw];
        }

        half8v ahf[4], alf[4], bhf[4];
        #pragma unroll
        for (int mf = 0; mf < 4; ++mf) {
            int m   = wr * 64 + mf * 16 + lrow;
            int off = m * 32 + ((lgrp ^ ((m >> 1) & 3)) << 3);
            ahf[mf] = *(half8v*)&Ah[off];
            alf[mf] = *(half8v*)&Al[off];
        }
        #pragma unroll
        for (int nf = 0; nf < 4; ++nf) {
            int nb  = wc * 4 + nf;
            int off = nb * 512 + ((lrow * 4 + (lgrp ^ ((lrow >> 1) & 3))) << 3);
            bhf[nf] = *(half8v*)&Bh[off];
        }

        #pragma unroll
        for (int mf = 0; mf < 4; ++mf)
            #pragma unroll
            for (int nf = 0; nf < 4; ++nf) {
                acc[mf][nf] = __builtin_amdgcn_mfma_f32_16x16x32_f16(ahf[mf], bhf[nf], acc[mf][nf], 0, 0, 0);
                acc[mf][nf] = __builtin_amdgcn_mfma_f32_16x16x32_f16(alf[mf], bhf[nf], acc[mf][nf], 0, 0, 0);
            }
    }

    #pragma unroll
    for (int nf = 0; nf < 4; ++nf) {
        int col = bn + wc * 64 + nf * 16 + lrow;
        float bb = bias[col];
        #pragma unroll
        for (int mf = 0; mf < 4; ++mf) {
            int row0 = bm + wr * 64 + mf * 16 + lgrp * 4;
            #pragma unroll
            for (int r = 0; r < 4; ++r) {
                float v = acc[mf][nf][r] + bb;
                C[(size_t)(row0 + r) * FDIM + col] = (v > 0.0f) ? v : 0.0f;
            }
        }
    }
}

// ---------------------------------------------------------------------------
// Fused top-k + decode — round-14 validated verbatim.
// ---------------------------------------------------------------------------
#define MAXCAND  32
#define LISTCAP  96

__global__ __launch_bounds__(512) void topk_decode(
    float* __restrict__ feat,
    const float* __restrict__ x,
    const float* __restrict__ Wenc,
    const float* __restrict__ WencT,
    const float* __restrict__ benc,
    const float* __restrict__ Wdec,
    const ushort* __restrict__ Wb,
    const float* __restrict__ bdec,
    const float* __restrict__ dmask,
    float* __restrict__ recon,
    float eps)
{
    int b   = blockIdx.x;
    int tid = threadIdx.x;
    int wv  = tid >> 6;
    int lane = tid & 63;
    float* frow = feat + (size_t)b * FDIM;

    float r[32];
    #pragma unroll
    for (int i = 0; i < 32; ++i) r[i] = frow[tid + i * 512];

    __shared__ uint32_t hist[8][256];
    __shared__ uint32_t scan[256];
    __shared__ uint32_t sh_prefix, sh_rem;
    __shared__ int   s_ncand, s_ndef, s_n;
    __shared__ int   s_cidx[MAXCAND];
    __shared__ float s_cval[MAXCAND];
    __shared__ int   s_sel[MAXCAND];
    __shared__ int   L_idx[LISTCAP];
    __shared__ float L_v0[LISTCAP], L_v1[LISTCAP];
    __shared__ double s_exact[MAXCAND];

    if (tid == 0) { s_ncand = 0; s_ndef = 0; s_n = 0; }

    #pragma unroll
    for (int i = 0; i < 4; ++i) ((uint32_t*)hist)[tid + i * 512] = 0u;
    __syncthreads();
    #pragma unroll
    for (int i = 0; i < 32; ++i) {
        uint32_t u = __float_as_uint(r[i]);
        if (u) atomicAdd(&hist[wv][u >> 24], 1u);
    }
    __syncthreads();
    if (tid < 256) {
        int rb = 255 - tid;
        uint32_t s = 0;
        #pragma unroll
        for (int w = 0; w < 8; ++w) s += hist[w][rb];
        scan[tid] = s;
    }
    __syncthreads();
    #pragma unroll
    for (int ofs = 1; ofs < 256; ofs <<= 1) {
        uint32_t tv = 0;
        if (tid < 256 && tid >= ofs) tv = scan[tid - ofs];
        __syncthreads();
        if (tid < 256) scan[tid] += tv;
        __syncthreads();
    }
    bool small = (scan[255] <= TOPK);

    uint32_t prefix = 0, rem = TOPK;
    if (!small) {
        if (tid < 256) {
            uint32_t cum  = scan[tid];
            uint32_t prev = (tid == 0) ? 0u : scan[tid - 1];
            if (cum >= rem && prev < rem) {
                sh_prefix = (uint32_t)(255 - tid);
                sh_rem    = rem - prev;
            }
        }
        __syncthreads();
        prefix = sh_prefix;
        rem    = sh_rem;
        __syncthreads();

        for (int byt = 2; byt >= 0; --byt) {
            #pragma unroll
            for (int i = 0; i < 4; ++i) ((uint32_t*)hist)[tid + i * 512] = 0u;
            __syncthreads();
            int shift_hi = (byt + 1) * 8;
            #pragma unroll
            for (int i = 0; i < 32; ++i) {
                uint32_t u = __float_as_uint(r[i]);
                if ((u >> shift_hi) == prefix)
                    atomicAdd(&hist[wv][(u >> (byt * 8)) & 255u], 1u);
            }
            __syncthreads();
            if (tid < 256) {
                int rb = 255 - tid;
                uint32_t s = 0;
                #pragma unroll
                for (int w = 0; w < 8; ++w) s += hist[w][rb];
                scan[tid] = s;
            }
            __syncthreads();
            #pragma unroll
            for (int ofs = 1; ofs < 256; ofs <<= 1) {
                uint32_t tv = 0;
                if (tid < 256 && tid >= ofs) tv = scan[tid - ofs];
                __syncthreads();
                if (tid < 256) scan[tid] += tv;
                __syncthreads();
            }
            if (tid < 256) {
                uint32_t cum  = scan[tid];
                uint32_t prev = (tid == 0) ? 0u : scan[tid - 1];
                if (cum >= rem && prev < rem) {
                    sh_prefix = (prefix << 8) | (uint32_t)(255 - tid);
                    sh_rem    = rem - prev;
                }
            }
            __syncthreads();
            prefix = sh_prefix;
            rem    = sh_rem;
            __syncthreads();
        }

        float T  = __uint_as_float(prefix);
        float hi = T + eps;
        float lo = T - eps;

        int mydef = 0;
        #pragma unroll
        for (int i = 0; i < 32; ++i) {
            float val = r[i];
            int   f   = tid + i * 512;
            if (val > hi) {
                ++mydef;
                int s = atomicAdd(&s_n, 1);
                if (s < LISTCAP) {
                    L_idx[s] = f;
                    L_v0[s]  = val * dmask[2 * f + 0];
                    L_v1[s]  = val * dmask[2 * f + 1];
                }
            } else if (val >= lo && val > 0.0f) {
                int s = atomicAdd(&s_ncand, 1);
                if (s < MAXCAND) { s_cidx[s] = f; s_cval[s] = val; }
                r[i] = 0.0f;
            } else {
                r[i] = 0.0f;
            }
        }
        atomicAdd(&s_ndef, mydef);
        #pragma unroll
        for (int i = 0; i < 32; ++i) frow[tid + i * 512] = r[i];
        __syncthreads();

        int A    = (s_ncand < MAXCAND) ? s_ncand : MAXCAND;
        int need = TOPK - s_ndef;

        if (A > need) {
            const float* xr = x + (size_t)b * KDIM;
            if (WencT != nullptr) {
                const float4* x4 = (const float4*)xr;
                for (int c0 = 0; c0 < A; c0 += 8) {
                    int c = c0 + wv;
                    if (c < A) {
                        int f = s_cidx[c];
                        const float4* wt = (const float4*)(WencT + (size_t)f * KDIM);
                        double s = 0.0;
                        #pragma unroll
                        for (int i = 0; i < 16; ++i) {
                            float4 wv4 = wt[lane + i * 64];
                            float4 xv4 = x4[lane + i * 64];
                            s += (double)xv4.x * (double)wv4.x + (double)xv4.y * (double)wv4.y
                               + (double)xv4.z * (double)wv4.z + (double)xv4.w * (double)wv4.w;
                        }
                        #pragma unroll
                        for (int ofs = 32; ofs > 0; ofs >>= 1)
                            s += __shfl_down(s, ofs, 64);
                        if (lane == 0) s_exact[c] = s + (double)benc[f];
                    }
                }
            } else {
                for (int c0 = 0; c0 < A; c0 += 8) {
                    int c = c0 + wv;
                    if (c < A) {
                        int f = s_cidx[c];
                        double s = 0.0;
                        #pragma unroll 8
                        for (int i = 0; i < 64; ++i) {
                            int k = lane + i * 64;
                            s += (double)xr[k] * (double)Wenc[(size_t)k * FDIM + f];
                        }
                        #pragma unroll
                        for (int ofs = 32; ofs > 0; ofs >>= 1)
                            s += __shfl_down(s, ofs, 64);
                        if (lane == 0) s_exact[c] = s + (double)benc[f];
                    }
                }
            }
            __syncthreads();
            if (tid == 0) {
                for (int c = 0; c < A; ++c) s_sel[c] = 0;
                for (int rr = 0; rr < need; ++rr) {
                    int best = -1;
                    for (int c = 0; c < A; ++c) {
                        if (s_sel[c]) continue;
                        if (best < 0 || s_exact[c] > s_exact[best] ||
                            (s_exact[c] == s_exact[best] && s_cidx[c] < s_cidx[best]))
                            best = c;
                    }
                    if (best >= 0) s_sel[best] = 1;
                }
            }
        } else {
            if (tid == 0)
                for (int c = 0; c < A; ++c) s_sel[c] = 1;
        }
        __syncthreads();

        if (tid < A && s_sel[tid]) {
            int   f   = s_cidx[tid];
            float val = s_cval[tid];
            frow[f] = val;
            int s = atomicAdd(&s_n, 1);
            if (s < LISTCAP) {
                L_idx[s] = f;
                L_v0[s]  = val * dmask[2 * f + 0];
                L_v1[s]  = val * dmask[2 * f + 1];
            }
        }
        __syncthreads();
    } else {
        #pragma unroll
        for (int i = 0; i < 32; ++i) {
            float val = r[i];
            if (val != 0.0f) {
                int f = tid + i * 512;
                int s = atomicAdd(&s_n, 1);
                if (s < LISTCAP) {
                    L_idx[s] = f;
                    L_v0[s]  = val * dmask[2 * f + 0];
                    L_v1[s]  = val * dmask[2 * f + 1];
                }
            }
        }
        __syncthreads();
    }

    int n = (s_n < LISTCAP) ? s_n : LISTCAP;

    const float4* b4 = (const float4*)bdec;
    float4 a0 = b4[tid];
    float4 a1 = b4[tid + 512];

    if (Wb != nullptr) {
        #pragma unroll 4
        for (int t = 0; t < n; ++t) {
            int f = L_idx[t];
            float s0 = L_v0[t], s1 = L_v1[t];
            const ushort4* w = (const ushort4*)(Wb + (size_t)f * DDIM);
            ushort4 u0 = w[tid];
            ushort4 u1 = w[tid + 512];
            a0.x = fmaf(s0, __uint_as_float((uint32_t)u0.x << 16), a0.x);
            a0.y = fmaf(s0, __uint_as_float((uint32_t)u0.y << 16), a0.y);
            a0.z = fmaf(s0, __uint_as_float((uint32_t)u0.z << 16), a0.z);
            a0.w = fmaf(s0, __uint_as_float((uint32_t)u0.w << 16), a0.w);
            a1.x = fmaf(s1, __uint_as_float((uint32_t)u1.x << 16), a1.x);
            a1.y = fmaf(s1, __uint_as_float((uint32_t)u1.y << 16), a1.y);
            a1.z = fmaf(s1, __uint_as_float((uint32_t)u1.z << 16), a1.z);
            a1.w = fmaf(s1, __uint_as_float((uint32_t)u1.w << 16), a1.w);
        }
    } else {
        #pragma unroll 4
        for (int t = 0; t < n; ++t) {
            int f = L_idx[t];
            float s0 = L_v0[t], s1 = L_v1[t];
            const float4* w = (const float4*)(Wdec + (size_t)f * DDIM);
            float4 w0 = w[tid];
            float4 w1 = w[tid + 512];
            a0.x = fmaf(s0, w0.x, a0.x); a0.y = fmaf(s0, w0.y, a0.y);
            a0.z = fmaf(s0, w0.z, a0.z); a0.w = fmaf(s0, w0.w, a0.w);
            a1.x = fmaf(s1, w1.x, a1.x); a1.y = fmaf(s1, w1.y, a1.y);
            a1.z = fmaf(s1, w1.z, a1.z); a1.w = fmaf(s1, w1.w, a1.w);
        }
    }

    float4* out = (float4*)(recon + (size_t)b * DDIM);
    out[tid]       = a0;
    out[tid + 512] = a1;
}

// ---------------------------------------------------------------------------
extern "C" void kernel_launch(void* const* d_in, const int* in_sizes, int n_in,
                              void* d_out, int out_size, void* d_ws, size_t ws_size,
                              hipStream_t stream)
{
    const float* x     = (const float*)d_in[0];
    const float* Wenc  = (const float*)d_in[1];
    const float* benc  = (const float*)d_in[2];
    const float* Wdec  = (const float*)d_in[3];
    const float* bdec  = (const float*)d_in[4];
    const float* dmask = (const float*)d_in[5];

    float* recon = (float*)d_out;
    float* feat  = recon + (size_t)BATCH * DDIM;

    const size_t MB = 1024 * 1024;
    // ws layout (full): [WencT f32 256MB][Wdec-bf16 128MB]
    bool wt    = (ws_size >= 256 * MB);
    bool wball = (ws_size >= 384 * MB);

    char* wsb = (char*)d_ws;
    float* WencT = wt ? (float*)wsb : nullptr;
    ushort* Wb = nullptr;
    if (wball)                         Wb = (ushort*)(wsb + 256 * MB);
    else if (!wt && ws_size >= 128*MB) Wb = (ushort*)wsb;   // round-12 behavior

    if (wt)
        transpose_wenc<<<dim3((KDIM / 64) * (FDIM / 64)), 256, 0, stream>>>(Wenc, WencT);
    if (Wb)
        wdec_to_bf16<<<dim3(2048), 256, 0, stream>>>(Wdec, Wb);

    float eps;
    if (wt) {
        eps = 1e-2f;   // 1-product encode error <= ~3.4e-3; cheap refinement
        encode_mfma_1p<<<dim3((BATCH / 128) * (FDIM / 128)), 256, 0, stream>>>(x, Wenc, benc, feat);
    } else {
        eps = 5e-3f;   // 2-product encode (round-12 exact config)
        encode_mfma<<<dim3((BATCH / 128) * (FDIM / 128)), 256, 0, stream>>>(x, Wenc, benc, feat);
    }

    topk_decode<<<dim3(BATCH), 512, 0, stream>>>(feat, x, Wenc, WencT, benc,
                                                 Wdec, Wb, bdec, dmask, recon, eps);
}